// Round 1
// baseline (1800.317 us; speedup 1.0000x reference)
//
#include <hip/hip_runtime.h>

// Problem constants
#define BB 8
#define SS 4096
#define DD 2048
#define HH 1024
#define EE 8
#define CHUNK 128
#define NCHUNK 32       // SS / CHUNK
#define TAU 0.7f

// GEMM tile config
#define BM 128
#define BN 128
#define BK 16

// ---------------------------------------------------------------------------
// Fused router kernel: for one (batch,chunk) x one 128-wide H slice, compute
//   acc[m][h] = x[m,:] @ W1[:,h]      (m in chunk's 128 tokens)
//   part[e]  += relu(acc + b1[h]) * W2[h,e]  summed over m,h
// then (1/128)*part atomically accumulated into chunk_logits[b,c,e].
// Grid: (H/BN = 8, B*NCHUNK = 256), block 256 threads.
// ---------------------------------------------------------------------------
__global__ __launch_bounds__(256) void router_gemm_kernel(
    const float* __restrict__ x,    // [B,S,D]
    const float* __restrict__ W1,   // [D,H]
    const float* __restrict__ b1,   // [H]
    const float* __restrict__ W2,   // [H,E]
    float* __restrict__ chunk_logits) // [B,NCHUNK,E], pre-zeroed
{
    const int slice = blockIdx.x;           // H slice index, 0..7
    const int bc    = blockIdx.y;           // batch*NCHUNK + chunk
    const int batch = bc / NCHUNK;
    const int chunk = bc % NCHUNK;

    const int tid = threadIdx.x;            // 0..255
    const int tx  = tid & 15;               // n-tile coord, 0..15
    const int ty  = tid >> 4;               // m-tile coord, 0..15

    __shared__ float As[BK][BM];            // k-major (transposed) -> frag reads contiguous in m
    __shared__ float Bs[BK][BN];
    __shared__ float W2s[BN][EE];           // 128 x 8
    __shared__ float b1s[BN];
    __shared__ float red[4][EE];            // cross-wave reduction

    const float* xrow  = x  + ((size_t)batch * SS + (size_t)chunk * CHUNK) * DD;
    const float* w1col = W1 + slice * BN;

    // Stage W2 slice (1024 floats -> 1 float4/thread) and b1 slice (128 floats)
    ((float4*)&W2s[0][0])[tid] = ((const float4*)(W2 + (size_t)slice * BN * EE))[tid];
    if (tid < BN / 4) {
        ((float4*)b1s)[tid] = ((const float4*)(b1 + slice * BN))[tid];
    }

    float acc[8][8];
#pragma unroll
    for (int i = 0; i < 8; ++i)
#pragma unroll
        for (int j = 0; j < 8; ++j) acc[i][j] = 0.0f;

    for (int k0 = 0; k0 < DD; k0 += BK) {
        // Load A tile: 128 m x 16 k = 2048 floats = 512 float4; 2 per thread.
        // Thread li: m = li/4, kg = li%4 (4 consecutive lanes cover 64B of one row).
#pragma unroll
        for (int r = 0; r < 2; ++r) {
            const int li = tid + r * 256;          // 0..511
            const int m  = li >> 2;
            const int kg = li & 3;
            float4 v = *(const float4*)(xrow + (size_t)m * DD + k0 + kg * 4);
            As[kg * 4 + 0][m] = v.x;
            As[kg * 4 + 1][m] = v.y;
            As[kg * 4 + 2][m] = v.z;
            As[kg * 4 + 3][m] = v.w;
        }
        // Load B tile: 16 k x 128 h = 2048 floats; row-contiguous float4 stores.
#pragma unroll
        for (int r = 0; r < 2; ++r) {
            const int li = tid + r * 256;          // 0..511
            const int kk = li >> 5;                // 0..15
            const int ng = li & 31;                // float4 index within row
            float4 v = *(const float4*)(w1col + (size_t)(k0 + kk) * HH + ng * 4);
            ((float4*)&Bs[kk][0])[ng] = v;
        }
        __syncthreads();

#pragma unroll
        for (int kk = 0; kk < BK; ++kk) {
            const float4 a0 = ((const float4*)&As[kk][0])[ty * 2];
            const float4 a1 = ((const float4*)&As[kk][0])[ty * 2 + 1];
            const float4 q0 = ((const float4*)&Bs[kk][0])[tx * 2];
            const float4 q1 = ((const float4*)&Bs[kk][0])[tx * 2 + 1];
            const float av[8] = {a0.x, a0.y, a0.z, a0.w, a1.x, a1.y, a1.z, a1.w};
            const float bv[8] = {q0.x, q0.y, q0.z, q0.w, q1.x, q1.y, q1.z, q1.w};
#pragma unroll
            for (int i = 0; i < 8; ++i)
#pragma unroll
                for (int j = 0; j < 8; ++j)
                    acc[i][j] = fmaf(av[i], bv[j], acc[i][j]);
        }
        __syncthreads();
    }

    // Epilogue: relu + second GEMM + partial chunk-sum, all in-register.
    float part[EE];
#pragma unroll
    for (int e = 0; e < EE; ++e) part[e] = 0.0f;

#pragma unroll
    for (int j = 0; j < 8; ++j) {
        const int hh = tx * 8 + j;             // local h within slice
        const float bias = b1s[hh];
        float w2r[EE];
#pragma unroll
        for (int e = 0; e < EE; ++e) w2r[e] = W2s[hh][e];
#pragma unroll
        for (int i = 0; i < 8; ++i) {
            const float hv = fmaxf(acc[i][j] + bias, 0.0f);
#pragma unroll
            for (int e = 0; e < EE; ++e) part[e] = fmaf(hv, w2r[e], part[e]);
        }
    }

    // Wave (64-lane) butterfly reduce, then cross-wave via LDS.
#pragma unroll
    for (int off = 32; off >= 1; off >>= 1) {
#pragma unroll
        for (int e = 0; e < EE; ++e) part[e] += __shfl_down(part[e], off, 64);
    }
    const int wave = tid >> 6;
    const int lane = tid & 63;
    if (lane == 0) {
#pragma unroll
        for (int e = 0; e < EE; ++e) red[wave][e] = part[e];
    }
    __syncthreads();
    if (tid < EE) {
        const float s = red[0][tid] + red[1][tid] + red[2][tid] + red[3][tid];
        atomicAdd(&chunk_logits[(size_t)bc * EE + tid], s * (1.0f / CHUNK));
    }
}

// ---------------------------------------------------------------------------
// Zero the chunk_logits accumulator (ws is poisoned 0xAA before every launch).
// ---------------------------------------------------------------------------
__global__ void zero_kernel(float* __restrict__ p, int n)
{
    const int i = blockIdx.x * blockDim.x + threadIdx.x;
    if (i < n) p[i] = 0.0f;
}

// ---------------------------------------------------------------------------
// Sequential hysteresis scan: one thread per batch (8 total).
// expert_indices written both as int (ws, for one-hot kernel) and as float
// (tail of d_out, matching harness float32 readback).
// ---------------------------------------------------------------------------
__global__ void hysteresis_kernel(const float* __restrict__ chunk_logits,
                                  const float* __restrict__ b2,
                                  int* __restrict__ eidx_ws,
                                  float* __restrict__ out_idx)
{
    const int b = threadIdx.x;
    if (b >= BB) return;
    const float* cl = chunk_logits + (size_t)b * NCHUNK * EE;
    int prev = 0;
    for (int c = 0; c < NCHUNK; ++c) {
        float v[EE];
        float best = -3.4e38f;
        int ce = 0;
#pragma unroll
        for (int e = 0; e < EE; ++e) {
            const float lv = cl[c * EE + e] + b2[e];
            v[e] = lv;
            if (lv > best) { best = lv; ce = e; }   // strict > => first-max, matches argmax
        }
        if (c == 0) {
            prev = ce;
        } else if (best - v[prev] > TAU) {
            prev = ce;
        }
        eidx_ws[b * NCHUNK + c] = prev;
        out_idx[b * NCHUNK + c] = (float)prev;
    }
}

// ---------------------------------------------------------------------------
// One-hot routing weights: one thread per token, two float4 stores.
// ---------------------------------------------------------------------------
__global__ __launch_bounds__(256) void onehot_kernel(const int* __restrict__ eidx,
                                                     float* __restrict__ out)
{
    const int tok = blockIdx.x * blockDim.x + threadIdx.x;   // 0..B*S-1
    if (tok >= BB * SS) return;
    const int b = tok / SS;
    const int s = tok - b * SS;
    const int idx = eidx[b * NCHUNK + (s / CHUNK)];
    float vals[EE];
#pragma unroll
    for (int e = 0; e < EE; ++e) vals[e] = (e == idx) ? 1.0f : 0.0f;
    float4* o = (float4*)(out + (size_t)tok * EE);
    o[0] = make_float4(vals[0], vals[1], vals[2], vals[3]);
    o[1] = make_float4(vals[4], vals[5], vals[6], vals[7]);
}

// ---------------------------------------------------------------------------
extern "C" void kernel_launch(void* const* d_in, const int* in_sizes, int n_in,
                              void* d_out, int out_size, void* d_ws, size_t ws_size,
                              hipStream_t stream)
{
    const float* x  = (const float*)d_in[0];   // [8,4096,2048]
    const float* W1 = (const float*)d_in[1];   // [2048,1024]
    const float* b1 = (const float*)d_in[2];   // [1024]
    const float* W2 = (const float*)d_in[3];   // [1024,8]
    const float* b2 = (const float*)d_in[4];   // [8]
    float* out = (float*)d_out;                // 262144 routing + 256 indices

    float* chunk_logits = (float*)d_ws;                        // 2048 floats
    int*   eidx         = (int*)((char*)d_ws + 2048 * sizeof(float)); // 256 ints

    // 1. zero accumulator (ws is re-poisoned 0xAA before every launch)
    zero_kernel<<<8, 256, 0, stream>>>(chunk_logits, BB * NCHUNK * EE);

    // 2. fused MLP + chunk-mean -> chunk_logits
    dim3 grid(HH / BN, BB * NCHUNK);           // (8, 256)
    router_gemm_kernel<<<grid, 256, 0, stream>>>(x, W1, b1, W2, chunk_logits);

    // 3. sequential hysteresis scan -> expert indices
    hysteresis_kernel<<<1, 64, 0, stream>>>(chunk_logits, b2, eidx,
                                            out + (size_t)BB * SS * EE);

    // 4. one-hot routing weights
    onehot_kernel<<<(BB * SS + 255) / 256, 256, 0, stream>>>(eidx, out);
}

// Round 2
// 715.180 us; speedup vs baseline: 2.5173x; 2.5173x over previous
//
#include <hip/hip_runtime.h>

typedef unsigned int uint;
typedef unsigned short ushort;

// Problem constants
#define BB 8
#define SS 4096
#define DD 2048
#define HH 1024
#define EE 8
#define CHUNK 128
#define NCHUNK 32
#define TAU 0.7f

// GEMM tile config
#define BM 128
#define BN 128
#define BK 32          // k per LDS buffer (4 groups of 8)
#define KITERS (DD / BK)

typedef short bf16x8 __attribute__((ext_vector_type(8)));    // 8 bf16 = 4 VGPRs
typedef float f32x16 __attribute__((ext_vector_type(16)));   // 32x32 C frag

// bf16 split helpers: hi = truncate-top-16(x); lo = bf16(x - hi)
__device__ inline uint pack_hi(float a, float b) {
    return (__float_as_uint(a) >> 16) | (__float_as_uint(b) & 0xFFFF0000u);
}
__device__ inline float hi_part(float a) {
    return __uint_as_float(__float_as_uint(a) & 0xFFFF0000u);
}

// ---------------------------------------------------------------------------
// Pre-pass: reorder W1 [D][H] fp32 -> W1hi/W1lo bf16 in MFMA-B-staged layout
// [D/8][H][8] (k-group major, 8 consecutive k per 16B). One thread per (kg,n).
// ---------------------------------------------------------------------------
__global__ __launch_bounds__(256) void reorder_w1_kernel(
    const float* __restrict__ W1, ushort* __restrict__ w1hi, ushort* __restrict__ w1lo)
{
    const int kg = blockIdx.x >> 2;                       // 0..255
    const int n  = ((blockIdx.x & 3) << 8) + threadIdx.x; // 0..1023
    float v[8];
#pragma unroll
    for (int j = 0; j < 8; ++j) v[j] = W1[(size_t)(kg * 8 + j) * HH + n];
    uint hi[4], lo[4];
#pragma unroll
    for (int p = 0; p < 4; ++p) {
        const float a = v[2 * p], b = v[2 * p + 1];
        hi[p] = pack_hi(a, b);
        lo[p] = pack_hi(a - hi_part(a), b - hi_part(b));
    }
    const size_t off = (size_t)kg * HH + n;               // uint4 index
    ((uint4*)w1hi)[off] = make_uint4(hi[0], hi[1], hi[2], hi[3]);
    ((uint4*)w1lo)[off] = make_uint4(lo[0], lo[1], lo[2], lo[3]);
}

// ---------------------------------------------------------------------------
// Fused router GEMM: one block = one (batch,chunk) x one 128-wide H slice.
// 3-term bf16-split MFMA (32x32x16). Epilogue: relu + W2 + chunk-sum ->
// atomicAdd into chunk_logits.
// ---------------------------------------------------------------------------
__global__ __launch_bounds__(256, 2) void router_gemm_kernel(
    const float* __restrict__ x,
    const ushort* __restrict__ w1hi,   // [D/8][H][8] bf16 bits
    const ushort* __restrict__ w1lo,
    const float* __restrict__ b1,
    const float* __restrict__ W2,
    float* __restrict__ chunk_logits)  // [B*NCHUNK][E], pre-zeroed
{
    const int slice = blockIdx.x;      // 0..7  (H slice)
    const int bc    = blockIdx.y;      // 0..255 (batch*NCHUNK + chunk)
    const int n0    = slice * BN;

    const int tid  = threadIdx.x;      // 0..255
    const int wave = tid >> 6;         // 0..3
    const int lane = tid & 63;
    const int lm   = lane & 31;        // row/col within 32-tile
    const int kq   = lane >> 5;        // k-quadrant (0/1)
    const int wm   = (wave & 1) * 64;  // wave m offset
    const int wn   = (wave >> 1) * 64; // wave n offset

    __shared__ ushort As_hi[4][BM][8];   // [kg][m][8k] bf16 bits, 8KB
    __shared__ ushort As_lo[4][BM][8];
    __shared__ ushort Bs_hi[4][BN][8];   // [kg][n][8k]
    __shared__ ushort Bs_lo[4][BN][8];
    __shared__ float  W2s[BN][EE];
    __shared__ float  b1s[BN];
    __shared__ float  red[4][EE];

    const float* xrow = x + (size_t)bc * CHUNK * DD;

    // Stage W2 slice + b1 slice
    ((float4*)&W2s[0][0])[tid] = ((const float4*)(W2 + (size_t)n0 * EE))[tid];
    if (tid < BN / 4) ((float4*)b1s)[tid] = ((const float4*)(b1 + n0))[tid];

    f32x16 acc[2][2];
#pragma unroll
    for (int i = 0; i < 2; ++i)
#pragma unroll
        for (int j = 0; j < 2; ++j)
#pragma unroll
            for (int r = 0; r < 16; ++r) acc[i][j][r] = 0.0f;

    // A staging coords: thread -> (m, k-half)
    const int am = tid >> 1;          // 0..127
    const int ah = tid & 1;           // 0/1: k0+ah*16 .. +16

    for (int it = 0; it < KITERS; ++it) {
        const int k0 = it * BK;
        __syncthreads();   // protect LDS from previous iteration's readers

        // ---- B tiles: async global->LDS, 16B/lane, zero VALU ----
        {
            const int kgg = (k0 >> 3) + wave;          // this wave's k-group
#pragma unroll
            for (int h = 0; h < 2; ++h) {
                const size_t goff = ((size_t)kgg * HH + n0 + h * 64 + lane) * 8; // ushort idx
                __builtin_amdgcn_global_load_lds(
                    (const __attribute__((address_space(1))) uint*)(w1hi + goff),
                    (__attribute__((address_space(3))) uint*)&Bs_hi[wave][h * 64 + lane][0],
                    16, 0, 0);
                __builtin_amdgcn_global_load_lds(
                    (const __attribute__((address_space(1))) uint*)(w1lo + goff),
                    (__attribute__((address_space(3))) uint*)&Bs_lo[wave][h * 64 + lane][0],
                    16, 0, 0);
            }
        }

        // ---- A tile: load fp32, split to bf16 hi/lo, write LDS ----
        {
            const float* src = xrow + (size_t)am * DD + k0 + ah * 16;
            float4 v0 = ((const float4*)src)[0];
            float4 v1 = ((const float4*)src)[1];
            float4 v2 = ((const float4*)src)[2];
            float4 v3 = ((const float4*)src)[3];
            const float f[16] = {v0.x, v0.y, v0.z, v0.w, v1.x, v1.y, v1.z, v1.w,
                                 v2.x, v2.y, v2.z, v2.w, v3.x, v3.y, v3.z, v3.w};
            uint hi[8], lo[8];
#pragma unroll
            for (int p = 0; p < 8; ++p) {
                const float a = f[2 * p], b = f[2 * p + 1];
                hi[p] = pack_hi(a, b);
                lo[p] = pack_hi(a - hi_part(a), b - hi_part(b));
            }
            const int kg0 = ah * 2;
            *(uint4*)&As_hi[kg0][am][0]     = make_uint4(hi[0], hi[1], hi[2], hi[3]);
            *(uint4*)&As_hi[kg0 + 1][am][0] = make_uint4(hi[4], hi[5], hi[6], hi[7]);
            *(uint4*)&As_lo[kg0][am][0]     = make_uint4(lo[0], lo[1], lo[2], lo[3]);
            *(uint4*)&As_lo[kg0 + 1][am][0] = make_uint4(lo[4], lo[5], lo[6], lo[7]);
        }

        __syncthreads();   // drains vmcnt (global_load_lds) + lgkmcnt

        // ---- MFMA: 2 k-steps x 2x2 tiles x 3 split terms ----
#pragma unroll
        for (int s = 0; s < 2; ++s) {
            const int kg = 2 * s + kq;
            bf16x8 a_h[2], a_l[2], b_h[2], b_l[2];
#pragma unroll
            for (int i = 0; i < 2; ++i) {
                a_h[i] = *(const bf16x8*)&As_hi[kg][wm + i * 32 + lm][0];
                a_l[i] = *(const bf16x8*)&As_lo[kg][wm + i * 32 + lm][0];
            }
#pragma unroll
            for (int j = 0; j < 2; ++j) {
                b_h[j] = *(const bf16x8*)&Bs_hi[kg][wn + j * 32 + lm][0];
                b_l[j] = *(const bf16x8*)&Bs_lo[kg][wn + j * 32 + lm][0];
            }
#pragma unroll
            for (int i = 0; i < 2; ++i)
#pragma unroll
                for (int j = 0; j < 2; ++j) {
                    acc[i][j] = __builtin_amdgcn_mfma_f32_32x32x16_bf16(
                        a_l[i], b_h[j], acc[i][j], 0, 0, 0);
                    acc[i][j] = __builtin_amdgcn_mfma_f32_32x32x16_bf16(
                        a_h[i], b_l[j], acc[i][j], 0, 0, 0);
                    acc[i][j] = __builtin_amdgcn_mfma_f32_32x32x16_bf16(
                        a_h[i], b_h[j], acc[i][j], 0, 0, 0);
                }
        }
    }

    // ---- Epilogue: relu + second GEMM + chunk partial sum ----
    float part[EE];
#pragma unroll
    for (int e = 0; e < EE; ++e) part[e] = 0.0f;

#pragma unroll
    for (int j = 0; j < 2; ++j) {
        const int hl = wn + j * 32 + lm;       // local h (col of C)
        const float bias = b1s[hl];
        float w2r[EE];
#pragma unroll
        for (int e = 0; e < EE; ++e) w2r[e] = W2s[hl][e];
#pragma unroll
        for (int i = 0; i < 2; ++i)
#pragma unroll
            for (int r = 0; r < 16; ++r) {
                const float hv = fmaxf(acc[i][j][r] + bias, 0.0f);
#pragma unroll
                for (int e = 0; e < EE; ++e) part[e] = fmaf(hv, w2r[e], part[e]);
            }
    }

#pragma unroll
    for (int off = 32; off >= 1; off >>= 1)
#pragma unroll
        for (int e = 0; e < EE; ++e) part[e] += __shfl_down(part[e], off, 64);

    if (lane == 0)
#pragma unroll
        for (int e = 0; e < EE; ++e) red[wave][e] = part[e];
    __syncthreads();
    if (tid < EE) {
        const float s = red[0][tid] + red[1][tid] + red[2][tid] + red[3][tid];
        atomicAdd(&chunk_logits[(size_t)bc * EE + tid], s * (1.0f / CHUNK));
    }
}

// ---------------------------------------------------------------------------
// Hysteresis scan: LDS-preload all chunk logits, then per-batch serial scan.
// ---------------------------------------------------------------------------
__global__ void hysteresis_kernel(const float* __restrict__ chunk_logits,
                                  const float* __restrict__ b2,
                                  int* __restrict__ eidx_ws,
                                  float* __restrict__ out_idx)
{
    __shared__ float cls[BB * NCHUNK * EE];   // 2048 floats
    const int tid = threadIdx.x;              // 0..63
#pragma unroll
    for (int i = 0; i < 8; ++i)
        ((float4*)cls)[tid + i * 64] = ((const float4*)chunk_logits)[tid + i * 64];
    __syncthreads();

    const int b = tid;
    if (b >= BB) return;
    float b2r[EE];
#pragma unroll
    for (int e = 0; e < EE; ++e) b2r[e] = b2[e];

    const float* cl = cls + b * NCHUNK * EE;
    int prev = 0;
    for (int c = 0; c < NCHUNK; ++c) {
        float v[EE];
        float best = -3.4e38f;
        int ce = 0;
#pragma unroll
        for (int e = 0; e < EE; ++e) {
            const float lv = cl[c * EE + e] + b2r[e];
            v[e] = lv;
            if (lv > best) { best = lv; ce = e; }
        }
        if (c == 0) prev = ce;
        else if (best - v[prev] > TAU) prev = ce;
        eidx_ws[b * NCHUNK + c] = prev;
        out_idx[b * NCHUNK + c] = (float)prev;
    }
}

// ---------------------------------------------------------------------------
// One-hot routing weights: one thread per token, two float4 stores.
// ---------------------------------------------------------------------------
__global__ __launch_bounds__(256) void onehot_kernel(const int* __restrict__ eidx,
                                                     float* __restrict__ out)
{
    const int tok = blockIdx.x * blockDim.x + threadIdx.x;
    if (tok >= BB * SS) return;
    const int b = tok / SS;
    const int s = tok - b * SS;
    const int idx = eidx[b * NCHUNK + (s / CHUNK)];
    float vals[EE];
#pragma unroll
    for (int e = 0; e < EE; ++e) vals[e] = (e == idx) ? 1.0f : 0.0f;
    float4* o = (float4*)(out + (size_t)tok * EE);
    o[0] = make_float4(vals[0], vals[1], vals[2], vals[3]);
    o[1] = make_float4(vals[4], vals[5], vals[6], vals[7]);
}

// ---------------------------------------------------------------------------
extern "C" void kernel_launch(void* const* d_in, const int* in_sizes, int n_in,
                              void* d_out, int out_size, void* d_ws, size_t ws_size,
                              hipStream_t stream)
{
    const float* x  = (const float*)d_in[0];
    const float* W1 = (const float*)d_in[1];
    const float* b1 = (const float*)d_in[2];
    const float* W2 = (const float*)d_in[3];
    const float* b2 = (const float*)d_in[4];
    float* out = (float*)d_out;

    // ws layout: W1hi (4MB) | W1lo (4MB) | chunk_logits (8KB) | eidx (1KB)
    ushort* w1hi        = (ushort*)d_ws;
    ushort* w1lo        = (ushort*)((char*)d_ws + (size_t)4 * 1024 * 1024);
    float*  chunk_logits = (float*)((char*)d_ws + (size_t)8 * 1024 * 1024);
    int*    eidx        = (int*)((char*)d_ws + (size_t)8 * 1024 * 1024 + 8192);

    hipMemsetAsync(chunk_logits, 0, BB * NCHUNK * EE * sizeof(float), stream);

    reorder_w1_kernel<<<1024, 256, 0, stream>>>(W1, w1hi, w1lo);

    dim3 grid(HH / BN, BB * NCHUNK);   // (8, 256)
    router_gemm_kernel<<<grid, 256, 0, stream>>>(x, w1hi, w1lo, b1, W2, chunk_logits);

    hysteresis_kernel<<<1, 64, 0, stream>>>(chunk_logits, b2, eidx,
                                            out + (size_t)BB * SS * EE);

    onehot_kernel<<<(BB * SS + 255) / 256, 256, 0, stream>>>(eidx, out);
}